// Round 1
// baseline (197.147 us; speedup 1.0000x reference)
//
#include <hip/hip_runtime.h>
#include <math.h>

// Shapes: sat (128,4,64,16) f32, grd (128,4,64,16) f32
// Outputs (f32, concat): sat 524288 | grd 524288 | distance[g][s] 16384 | orien[s][g] 16384
#define N_S 128
#define N_G 128
#define H4 4
#define W64 64
#define C16 16
#define K_TOT 4096        // 4*64*16
#define SAT_STR 129       // padded LDS row stride (w' reaches 126, +pad)
#define GB 32             // g per block

#define GRD_T_OFF 0       // grdT staged in d_out[0..524287], overwritten later by sat copy
#define GRD_OFF   524288
#define DIST_OFF  1048576
#define ORI_OFF   1064960

// grdT[k][g], k = (h*16+c)*64 + dw
__global__ void transpose_grd_k(const float* __restrict__ grd, float* __restrict__ grdT) {
    int tid = blockIdx.x * 256 + threadIdx.x;   // 0..524287, g fastest -> coalesced writes
    int g  = tid & 127;
    int k  = tid >> 7;
    int dw = k & 63;
    int hc = k >> 6;
    int h  = hc >> 4;
    int c  = hc & 15;
    grdT[tid] = grd[((g * H4 + h) * W64 + dw) * C16 + c];
}

__global__ __launch_bounds__(256) void corr_k(const float* __restrict__ sat,
                                              const float* __restrict__ grdT,
                                              float* __restrict__ out) {
    __shared__ float satT[64 * SAT_STR];   // 33 KB: satT[hc][w'], w' in [0,127)
    __shared__ float tileBuf[64 * GB];     // 8 KB: grd tile, reused as corr buffer
    __shared__ float wpart[4];
    __shared__ float rnormS;

    const int tid = threadIdx.x;
    const int s   = blockIdx.x >> 2;
    const int g0  = (blockIdx.x & 3) * GB;

    // ---- Phase 0: stage sat[s] doubled along w into LDS + compute ||sat[s]|| ----
    const float* satS = sat + s * K_TOT;
    float ssq = 0.f;
    #pragma unroll
    for (int r = 0; r < 16; ++r) {
        int idx = r * 256 + tid;           // coalesced global read
        float v = satS[idx];
        int h = idx >> 10;
        int w = (idx >> 4) & 63;
        int c = idx & 15;
        int row = h * 16 + c;
        satT[row * SAT_STR + w] = v;
        if (w < 63) satT[row * SAT_STR + w + 64] = v;   // circular pad
        ssq += v * v;
    }
    #pragma unroll
    for (int off = 32; off > 0; off >>= 1) ssq += __shfl_down(ssq, off, 64);
    if ((tid & 63) == 0) wpart[tid >> 6] = ssq;
    __syncthreads();
    if (tid == 0)
        rnormS = 1.f / fmaxf(sqrtf(wpart[0] + wpart[1] + wpart[2] + wpart[3]), 1e-12f);

    // ---- Phase 1: corr[j, g] accumulation; thread = (tj: 4 j's) x (tg: 2 g's) ----
    const int tj = tid >> 4;     // 0..15 -> j0 = 4*tj covers j 0..63
    const int tg = tid & 15;     // 0..15 -> g pair 2*tg covers 0..31
    const int j0 = tj * 4;

    float a00 = 0.f, a01 = 0.f, a10 = 0.f, a11 = 0.f;
    float a20 = 0.f, a21 = 0.f, a30 = 0.f, a31 = 0.f;

    for (int hc = 0; hc < 64; ++hc) {
        __syncthreads();                       // tileBuf safe to overwrite
        #pragma unroll
        for (int i = 0; i < 8; ++i) {
            int e = i * 256 + tid;             // dw = e>>5, gg = e&31
            tileBuf[e] = grdT[(hc * 64 + (e >> 5)) * 128 + g0 + (e & 31)];
        }
        __syncthreads();

        const float* sr = &satT[hc * SAT_STR + j0];
        float w0 = sr[0], w1 = sr[1], w2 = sr[2];
        #pragma unroll 8
        for (int dw = 0; dw < 64; ++dw) {
            float w3 = sr[dw + 3];             // sliding window: 1 new b32 per step
            float2 g2 = *(const float2*)&tileBuf[dw * GB + tg * 2];
            a00 = fmaf(w0, g2.x, a00); a01 = fmaf(w0, g2.y, a01);
            a10 = fmaf(w1, g2.x, a10); a11 = fmaf(w1, g2.y, a11);
            a20 = fmaf(w2, g2.x, a20); a21 = fmaf(w2, g2.y, a21);
            a30 = fmaf(w3, g2.x, a30); a31 = fmaf(w3, g2.y, a31);
            w0 = w1; w1 = w2; w2 = w3;
        }
    }

    // ---- Phase 2: argmax over j per g, write distance + orien ----
    __syncthreads();
    tileBuf[(j0 + 0) * GB + tg * 2 + 0] = a00; tileBuf[(j0 + 0) * GB + tg * 2 + 1] = a01;
    tileBuf[(j0 + 1) * GB + tg * 2 + 0] = a10; tileBuf[(j0 + 1) * GB + tg * 2 + 1] = a11;
    tileBuf[(j0 + 2) * GB + tg * 2 + 0] = a20; tileBuf[(j0 + 2) * GB + tg * 2 + 1] = a21;
    tileBuf[(j0 + 3) * GB + tg * 2 + 0] = a30; tileBuf[(j0 + 3) * GB + tg * 2 + 1] = a31;
    __syncthreads();

    if (tid < GB) {
        int gg = tid;
        float best = tileBuf[gg];              // j = 0
        int bj = 0;
        for (int j = 1; j < 64; ++j) {
            float v = tileBuf[j * GB + gg];
            if (v > best) { best = v; bj = j; }   // strict > = numpy first-occurrence
        }
        float dot = best * rnormS;
        out[DIST_OFF + (g0 + gg) * N_S + s] = 2.f - 2.f * dot;   // distance = (2-2*dot).T
        out[ORI_OFF + s * N_G + g0 + gg]    = (float)bj;
    }
}

// Pass-through copies (also overwrites the grdT staging region)
__global__ void copy_k(const float4* __restrict__ a, const float4* __restrict__ b,
                       float4* __restrict__ out) {
    int i = blockIdx.x * 256 + threadIdx.x;    // 0..131071 per tensor (float4 units)
    out[i] = a[i];
    out[131072 + i] = b[i];
}

extern "C" void kernel_launch(void* const* d_in, const int* in_sizes, int n_in,
                              void* d_out, int out_size, void* d_ws, size_t ws_size,
                              hipStream_t stream) {
    const float* sat = (const float*)d_in[0];
    const float* grd = (const float*)d_in[1];
    float* out = (float*)d_out;

    // 1) grd -> grdT (staged in out[0..524287])
    transpose_grd_k<<<2048, 256, 0, stream>>>(grd, out + GRD_T_OFF);
    // 2) corr + argmax + distance + orien
    corr_k<<<512, 256, 0, stream>>>(sat, out + GRD_T_OFF, out);
    // 3) input pass-through copies (overwrite grdT region last)
    copy_k<<<512, 256, 0, stream>>>((const float4*)sat, (const float4*)grd, (float4*)out);
}

// Round 2
// 164.125 us; speedup vs baseline: 1.2012x; 1.2012x over previous
//
#include <hip/hip_runtime.h>
#include <math.h>

// Shapes: sat (128,4,64,16) f32, grd (128,4,64,16) f32
// Outputs (f32, concat): sat 524288 | grd 524288 | distance[g][s] 16384 | orien[s][g] 16384
#define N_S 128
#define N_G 128
#define K_TOT 4096
#define SAT_STR 129      // satT row stride (w' in [0,127))
#define RED_STR 33       // reduce buffer j-stride (32 g + 1 pad)
#define GRD_OFF   524288
#define DIST_OFF  1048576
#define ORI_OFF   1064960

// grdT[k][g], k = (h*16+c)*64 + dw  (row of 128 g per k)
__global__ void transpose_grd_k(const float* __restrict__ grd, float* __restrict__ grdT) {
    int tid = blockIdx.x * 256 + threadIdx.x;   // g fastest -> coalesced writes
    int g  = tid & 127;
    int k  = tid >> 7;
    int dw = k & 63;
    int hc = k >> 6;
    int h  = hc >> 4;
    int c  = hc & 15;
    grdT[tid] = grd[((g * 4 + h) * 64 + dw) * 16 + c];
}

// Block = (s, 32-g chunk). 4 waves split K (16 hc each), reduce via LDS at end.
// Thread tile: TJ=8 (LDS sliding window, 1 ds_read_b32/step) x TG=4 (global float4).
__global__ __launch_bounds__(256) void corr_k(const float* __restrict__ sat,
                                              const float* __restrict__ grdOrig,
                                              const float* __restrict__ grdT,
                                              float* __restrict__ out, int fuse) {
    __shared__ float lds[8448];   // satT: 64*129=8256 floats; reduce: 4*64*33=8448
    __shared__ float wpart[4];
    __shared__ float rnormS;

    const int tid = threadIdx.x;
    const int s   = blockIdx.x >> 2;
    const int g0  = (blockIdx.x & 3) * 32;

    // ---- Fused passthrough copies (overlapped with compute; grdT lives in d_ws) ----
    if (fuse) {
        const float4* s4 = (const float4*)sat;
        const float4* g4 = (const float4*)grdOrig;
        float4* o4 = (float4*)out;
        int base = blockIdx.x * 256 + tid;          // 0..131071
        o4[base] = s4[base];
        o4[131072 + base] = g4[base];
    }

    // ---- Phase 0: stage satT[hc][w'] doubled along w + compute ||sat[s]|| ----
    const float* satS = sat + s * K_TOT;
    float ssq = 0.f;
    #pragma unroll
    for (int r = 0; r < 16; ++r) {
        int idx = r * 256 + tid;
        float v = satS[idx];
        int h = idx >> 10;
        int w = (idx >> 4) & 63;
        int c = idx & 15;
        int row = h * 16 + c;
        lds[row * SAT_STR + w] = v;
        if (w < 63) lds[row * SAT_STR + w + 64] = v;
        ssq += v * v;
    }
    #pragma unroll
    for (int off = 32; off > 0; off >>= 1) ssq += __shfl_down(ssq, off, 64);
    if ((tid & 63) == 0) wpart[tid >> 6] = ssq;
    __syncthreads();
    if (tid == 0)
        rnormS = 1.f / fmaxf(sqrtf(wpart[0] + wpart[1] + wpart[2] + wpart[3]), 1e-12f);

    // ---- Phase 1: K-split accumulation. wave w: hc in [w*16, w*16+16) ----
    const int wv    = tid >> 6;
    const int lane  = tid & 63;
    const int jslot = lane >> 3;      // 8 slots of TJ=8 j's
    const int gslot = lane & 7;       // 8 slots of TG=4 g's
    const int j0    = jslot * 8;

    float acc[8][4];
    #pragma unroll
    for (int a = 0; a < 8; ++a)
        #pragma unroll
        for (int b = 0; b < 4; ++b) acc[a][b] = 0.f;

    for (int hc = wv * 16; hc < wv * 16 + 16; ++hc) {
        const float* sr = &lds[hc * SAT_STR + j0];
        const float* gp = grdT + (size_t)(hc * 64) * 128 + g0 + gslot * 4;
        float win[8];
        #pragma unroll
        for (int i = 0; i < 7; ++i) win[i] = sr[i];
        #pragma unroll 8
        for (int dw = 0; dw < 64; ++dw) {
            float4 gv = *(const float4*)(gp + (size_t)dw * 128);   // L2-resident, VMEM pipe
            win[7] = sr[dw + 7];                                   // 1 ds_read_b32/step
            #pragma unroll
            for (int jj = 0; jj < 8; ++jj) {
                float wvv = win[jj];
                acc[jj][0] = fmaf(wvv, gv.x, acc[jj][0]);
                acc[jj][1] = fmaf(wvv, gv.y, acc[jj][1]);
                acc[jj][2] = fmaf(wvv, gv.z, acc[jj][2]);
                acc[jj][3] = fmaf(wvv, gv.w, acc[jj][3]);
            }
            #pragma unroll
            for (int i = 0; i < 7; ++i) win[i] = win[i + 1];
        }
    }

    // ---- Phase 2: cross-wave reduce (satT is dead; reuse lds) ----
    __syncthreads();
    #pragma unroll
    for (int jj = 0; jj < 8; ++jj)
        #pragma unroll
        for (int gg = 0; gg < 4; ++gg)
            lds[wv * 2112 + (j0 + jj) * RED_STR + gslot * 4 + gg] = acc[jj][gg];
    __syncthreads();

    float cmb[8];
    #pragma unroll
    for (int i = 0; i < 8; ++i) {
        int c = tid + 256 * i;            // 2048 cells: j = c>>5, g = c&31
        int a = (c >> 5) * RED_STR + (c & 31);
        cmb[i] = lds[a] + lds[a + 2112] + lds[a + 4224] + lds[a + 6336];
    }
    __syncthreads();
    #pragma unroll
    for (int i = 0; i < 8; ++i) {
        int c = tid + 256 * i;
        lds[(c >> 5) * RED_STR + (c & 31)] = cmb[i];
    }
    __syncthreads();

    // ---- Phase 3: argmax over j (first-occurrence), distance + orien ----
    if (tid < 32) {
        float best = lds[tid];            // j = 0
        int bj = 0;
        for (int j = 1; j < 64; ++j) {
            float v = lds[j * RED_STR + tid];
            if (v > best) { best = v; bj = j; }
        }
        float dot = best * rnormS;
        out[DIST_OFF + (g0 + tid) * N_S + s] = 2.f - 2.f * dot;
        out[ORI_OFF + s * N_G + g0 + tid]    = (float)bj;
    }
}

// Fallback passthrough copies (only when grdT was staged inside d_out)
__global__ void copy_k(const float4* __restrict__ a, const float4* __restrict__ b,
                       float4* __restrict__ out) {
    int i = blockIdx.x * 256 + threadIdx.x;
    out[i] = a[i];
    out[131072 + i] = b[i];
}

extern "C" void kernel_launch(void* const* d_in, const int* in_sizes, int n_in,
                              void* d_out, int out_size, void* d_ws, size_t ws_size,
                              hipStream_t stream) {
    const float* sat = (const float*)d_in[0];
    const float* grd = (const float*)d_in[1];
    float* out = (float*)d_out;

    const bool useWs = (ws_size >= (size_t)K_TOT * 128 * sizeof(float));   // 2 MB
    float* grdT = useWs ? (float*)d_ws : out;          // else stage in out's sat region

    transpose_grd_k<<<2048, 256, 0, stream>>>(grd, grdT);
    corr_k<<<512, 256, 0, stream>>>(sat, grd, grdT, out, useWs ? 1 : 0);
    if (!useWs)
        copy_k<<<512, 256, 0, stream>>>((const float4*)sat, (const float4*)grd, (float4*)out);
}

// Round 3
// 106.408 us; speedup vs baseline: 1.8527x; 1.5424x over previous
//
#include <hip/hip_runtime.h>
#include <math.h>

typedef _Float16 f16;
typedef __attribute__((ext_vector_type(8))) _Float16 f16x8;
typedef __attribute__((ext_vector_type(16))) float f32x16;

// sat (128,4,64,16) f32, grd (128,4,64,16) f32
// out (f32): sat 524288 | grd 524288 | distance[g][s] 16384 | orien[s][g] 16384
#define DIST_OFF  1048576
#define ORI_OFF   1064960
#define SATP_STR  72              // f16 row stride = 144 B (16B-multiple), 64 cols + pad
#define SATP_ELEMS (127 * SATP_STR)

// k-order: k = dw*64 + (h*16+c).  grdF[k>>3][g][k&7] f16 (frag-ready, g-coalesced)
__global__ void grd_prep_k(const float* __restrict__ grd,
                           f16* __restrict__ gHi, f16* __restrict__ gLo) {
    int tau = blockIdx.x * 256 + threadIdx.x;   // 0..65535 = (kb 0..511, g 0..127)
    int kb = tau >> 7;
    int g  = tau & 127;
    int k0 = kb * 8;
    int dw = k0 >> 6;
    int hc0 = k0 & 63;                          // multiple of 8
    int h = hc0 >> 4, c0 = hc0 & 15;
    const float* in = grd + (((g * 4 + h) * 64 + dw) * 16 + c0);   // 8 contiguous c
    f16x8 hv, lv;
    #pragma unroll
    for (int i = 0; i < 8; ++i) {
        float v = in[i];
        f16 h16 = (f16)v;
        hv[i] = h16;
        lv[i] = (f16)(v - (float)h16);
    }
    ((f16x8*)gHi)[tau] = hv;
    ((f16x8*)gLo)[tau] = lv;
}

// Block = (s, g-half64). 8 waves = jt(2) x gt(2) x kh(2). Wave: 32j x 32g, K/2.
__global__ __launch_bounds__(512) void corr_k(const float* __restrict__ sat,
                                              const f16* __restrict__ gHi,
                                              const f16* __restrict__ gLo,
                                              float* __restrict__ out,
                                              const float4* __restrict__ satIn,
                                              const float4* __restrict__ grdIn,
                                              int fuse) {
    __shared__ __align__(16) unsigned char smemRaw[36864];
    __shared__ float wred[8];
    __shared__ float rnormS;
    f16* sH = (f16*)smemRaw;                 // satP hi: [w' 0..126][hc 0..63], stride 72
    f16* sL = sH + SATP_ELEMS;

    const int tid = threadIdx.x;
    const int s  = blockIdx.x >> 1;
    const int gh = blockIdx.x & 1;

    // fused passthrough copies (grdF lives in d_ws)
    if (fuse) {
        float4* o4 = (float4*)out;
        int i = blockIdx.x * 512 + tid;      // 0..131071
        o4[i] = satIn[i];
        o4[131072 + i] = grdIn[i];
    }

    // ---- stage satP hi/lo (doubled along w) + ||sat[s]||^2 ----
    const float* satS = sat + s * 4096;
    float ssq = 0.f;
    #pragma unroll
    for (int r = 0; r < 8; ++r) {
        int idx = r * 512 + tid;
        float v = satS[idx];
        int h = idx >> 10, w = (idx >> 4) & 63, c = idx & 15;
        int col = h * 16 + c;
        f16 hv = (f16)v;
        f16 lv = (f16)(v - (float)hv);
        sH[w * SATP_STR + col] = hv;
        sL[w * SATP_STR + col] = lv;
        if (w < 63) {
            sH[(w + 64) * SATP_STR + col] = hv;
            sL[(w + 64) * SATP_STR + col] = lv;
        }
        ssq += v * v;
    }
    #pragma unroll
    for (int off = 32; off > 0; off >>= 1) ssq += __shfl_down(ssq, off, 64);
    if ((tid & 63) == 0) wred[tid >> 6] = ssq;
    __syncthreads();
    if (tid == 0) {
        float t = 0.f;
        #pragma unroll
        for (int i = 0; i < 8; ++i) t += wred[i];
        rnormS = 1.f / fmaxf(sqrtf(t), 1e-12f);
    }
    __syncthreads();

    // ---- MFMA GEMM: C[j,g] += satP * grdF, 3-term fp16 split ----
    const int wave = tid >> 6, lane = tid & 63;
    const int jt = wave & 1, gt = (wave >> 1) & 1, kh = wave >> 2;
    const int m = lane & 31, half = lane >> 5;
    const int gg = gh * 64 + gt * 32 + m;            // global g for B frags
    const f16* Abh = sH + (jt * 32 + m) * SATP_STR;  // row base (dw=0)
    const f16* Abl = sL + (jt * 32 + m) * SATP_STR;
    const f16x8* BH = (const f16x8*)gHi;
    const f16x8* BL = (const f16x8*)gLo;

    f32x16 acc1, acc2;
    #pragma unroll
    for (int r = 0; r < 16; ++r) { acc1[r] = 0.f; acc2[r] = 0.f; }

    const int t0 = kh * 128;
    #pragma unroll 8
    for (int t = t0; t < t0 + 128; ++t) {
        int dw  = t >> 2;
        int hcb = (t & 3) * 16 + half * 8;
        f16x8 ah = *(const f16x8*)(Abh + dw * SATP_STR + hcb);   // ds_read_b128
        f16x8 al = *(const f16x8*)(Abl + dw * SATP_STR + hcb);
        int bu = (t * 2 + half) * 128 + gg;
        f16x8 bh = BH[bu];                                       // global dwordx4, L2
        f16x8 bl = BL[bu];
        acc1 = __builtin_amdgcn_mfma_f32_32x32x16_f16(ah, bh, acc1, 0, 0, 0);
        acc2 = __builtin_amdgcn_mfma_f32_32x32x16_f16(ah, bl, acc2, 0, 0, 0);
        acc2 = __builtin_amdgcn_mfma_f32_32x32x16_f16(al, bh, acc2, 0, 0, 0);
    }
    acc1 = acc1 + acc2;

    // ---- cross-kh reduce (satP dead; reuse smem) ----
    __syncthreads();
    float* red = (float*)smemRaw;            // 4 tiles x 1024 floats = 16 KB
    if (kh) {
        int base = (wave - 4) * 1024 + lane * 16;
        #pragma unroll
        for (int r = 0; r < 16; ++r) red[base + r] = acc1[r];
    }
    __syncthreads();
    float* argv = red + 4096;                // 4 waves x 32 lanes x 2
    if (!kh) {
        int base = wave * 1024 + lane * 16;
        #pragma unroll
        for (int r = 0; r < 16; ++r) acc1[r] += red[base + r];
        // argmax over this wave's 16 regs (j = jt*32 + (r&3)+8*(r>>2)+4*half)
        float best = acc1[0];
        int bj = jt * 32 + 4 * half;
        #pragma unroll
        for (int r = 1; r < 16; ++r) {
            int j = jt * 32 + (r & 3) + 8 * (r >> 2) + 4 * half;
            float v = acc1[r];
            if (v > best || (v == best && j < bj)) { best = v; bj = j; }
        }
        float ob = __shfl_xor(best, 32, 64);
        int  obj = __shfl_xor(bj, 32, 64);
        if (ob > best || (ob == best && obj < bj)) { best = ob; bj = obj; }
        if (lane < 32) {
            argv[(wave * 32 + lane) * 2]     = best;
            argv[(wave * 32 + lane) * 2 + 1] = (float)bj;
        }
    }
    __syncthreads();

    // ---- combine jt halves, write distance + orien ----
    if (tid < 64) {
        int gt2 = tid >> 5, g32 = tid & 31;
        int w0 = 2 * gt2, w1 = 2 * gt2 + 1;          // jt=0 wave, jt=1 wave
        float b0 = argv[(w0 * 32 + g32) * 2];
        float j0 = argv[(w0 * 32 + g32) * 2 + 1];
        float b1 = argv[(w1 * 32 + g32) * 2];
        float j1 = argv[(w1 * 32 + g32) * 2 + 1];
        float best = (b1 > b0) ? b1 : b0;            // tie -> jt0 (smaller j) = first occ.
        float bj   = (b1 > b0) ? j1 : j0;
        float dot = best * rnormS;
        int g = gh * 64 + gt2 * 32 + g32;
        out[DIST_OFF + g * 128 + s] = 2.f - 2.f * dot;
        out[ORI_OFF + s * 128 + g]  = bj;
    }
}

// Fallback passthrough copies (when grdF was staged inside d_out's sat region)
__global__ void copy_k(const float4* __restrict__ a, const float4* __restrict__ b,
                       float4* __restrict__ out) {
    int i = blockIdx.x * 256 + threadIdx.x;
    out[i] = a[i];
    out[131072 + i] = b[i];
}

extern "C" void kernel_launch(void* const* d_in, const int* in_sizes, int n_in,
                              void* d_out, int out_size, void* d_ws, size_t ws_size,
                              hipStream_t stream) {
    const float* sat = (const float*)d_in[0];
    const float* grd = (const float*)d_in[1];
    float* out = (float*)d_out;

    const bool useWs = (ws_size >= (size_t)2 * 1024 * 1024);
    f16* gHi;
    f16* gLo;
    if (useWs) {
        gHi = (f16*)d_ws;
        gLo = gHi + 524288;
    } else {
        gHi = (f16*)out;                 // floats [0, 262144)
        gLo = (f16*)(out + 262144);      // floats [262144, 524288)
    }

    grd_prep_k<<<256, 256, 0, stream>>>(grd, gHi, gLo);
    corr_k<<<256, 512, 0, stream>>>(sat, gHi, gLo, out,
                                    (const float4*)sat, (const float4*)grd,
                                    useWs ? 1 : 0);
    if (!useWs)
        copy_k<<<512, 256, 0, stream>>>((const float4*)sat, (const float4*)grd, (float4*)out);
}

// Round 4
// 87.453 us; speedup vs baseline: 2.2543x; 1.2167x over previous
//
#include <hip/hip_runtime.h>
#include <math.h>

typedef _Float16 f16;
typedef __attribute__((ext_vector_type(8))) _Float16 f16x8;
typedef __attribute__((ext_vector_type(16))) float f32x16;

// sat (128,4,64,16) f32, grd (128,4,64,16) f32
// out (f32): sat 524288 | grd 524288 | distance[g][s] 16384 | orien[s][g] 16384
#define DIST_OFF  1048576
#define ORI_OFF   1064960
#define SATP_STR  72      // f16 elems per satP row (144 B, 16B-multiple)

#define MFMA(a,b,c) __builtin_amdgcn_mfma_f32_32x32x16_f16((a),(b),(c),0,0,0)

// ---- prep: grd -> frag-ready grdF[kb][g][e] hi/lo (k = dw*64 + h*16 + c), LDS-tiled ----
// blocks 0..63: transpose/convert.  blocks 64..575 (optional): passthrough copies.
__global__ __launch_bounds__(256) void prep_k(const float* __restrict__ grd,
                                              f16* __restrict__ gHi, f16* __restrict__ gLo,
                                              const float4* __restrict__ satIn,
                                              const float4* __restrict__ grdIn,
                                              float4* __restrict__ out4) {
    const int b = blockIdx.x;
    if (b >= 64) {
        int i = (b - 64) * 256 + threadIdx.x;   // 0..131071 float4
        out4[i] = satIn[i];
        out4[131072 + i] = grdIn[i];
        return;
    }
    __shared__ f16 tH[8192], tL[8192];          // [kb_l 64][g_l 16][e 8]
    const int tid = threadIdx.x;
    const int g0 = (b & 7) * 16;
    const int kq = b >> 3;                      // k-range [kq*512, kq*512+512)
    #pragma unroll
    for (int i = 0; i < 32; ++i) {
        int flat = i * 256 + tid;               // [g_l 16][h 4][j 128], coalesced reads
        int g_l = flat >> 9;
        int r   = flat & 511;
        int h   = r >> 7;
        int j   = r & 127;                      // dw_l = j>>4, c = j&15
        float v = grd[(((g0 + g_l) * 4 + h) * 64 + kq * 8) * 16 + j];
        int k_l = (j >> 4) * 64 + h * 16 + (j & 15);
        f16 hv = (f16)v;
        int a = (k_l >> 3) * 128 + g_l * 8 + (k_l & 7);
        tH[a] = hv;
        tL[a] = (f16)(v - (float)hv);
    }
    __syncthreads();
    #pragma unroll
    for (int i = 0; i < 4; ++i) {
        int f = i * 256 + tid;                  // frag: kb_l = f>>4, g_l = f&15
        int dst = (kq * 64 + (f >> 4)) * 128 + g0 + (f & 15);
        ((f16x8*)gHi)[dst] = *(const f16x8*)(tH + f * 8);
        ((f16x8*)gLo)[dst] = *(const f16x8*)(tL + f * 8);
    }
}

// ---- corr: block=(s, g-half64), 8 waves = 8-way K split, wave tile 64j x 64g ----
__global__ __launch_bounds__(512, 2) void corr_k(const float* __restrict__ sat,
                                                 const f16* __restrict__ gHi,
                                                 const f16* __restrict__ gLo,
                                                 float* __restrict__ out) {
    __shared__ __align__(16) unsigned char smem[131072];  // satP (36.6KB) then red (128KB)
    __shared__ float wred[8];
    __shared__ float rnormS;
    f16* sH = (f16*)smem;                 // [w' 0..126][hc 0..63], stride 72
    f16* sL = sH + 127 * SATP_STR;
    float* red = (float*)smem;            // [kh 8][j 64][g 64]

    const int tid = threadIdx.x;
    const int s  = blockIdx.x >> 1;
    const int gh = blockIdx.x & 1;
    const int wave = tid >> 6, lane = tid & 63;
    const int m = lane & 31, half = lane >> 5;

    // ---- stage satP hi/lo (doubled along w) + ||sat[s]||^2 ----
    const float* satS = sat + s * 4096;
    float ssq = 0.f;
    #pragma unroll
    for (int r = 0; r < 8; ++r) {
        int idx = r * 512 + tid;
        float v = satS[idx];
        int h = idx >> 10, w = (idx >> 4) & 63, c = idx & 15;
        int col = h * 16 + c;
        f16 hv = (f16)v, lv = (f16)(v - (float)hv);
        sH[w * SATP_STR + col] = hv;
        sL[w * SATP_STR + col] = lv;
        if (w < 63) { sH[(w + 64) * SATP_STR + col] = hv; sL[(w + 64) * SATP_STR + col] = lv; }
        ssq += v * v;
    }
    #pragma unroll
    for (int off = 32; off > 0; off >>= 1) ssq += __shfl_down(ssq, off, 64);
    if (lane == 0) wred[wave] = ssq;
    __syncthreads();
    if (tid == 0) {
        float t = 0.f;
        #pragma unroll
        for (int i = 0; i < 8; ++i) t += wred[i];
        rnormS = 1.f / fmaxf(sqrtf(t), 1e-12f);
    }

    // ---- K-loop: kh = wave, 32 k-tiles of 16; 2x2 MFMA subtiles, 1-deep prefetch ----
    const f16* A0h = sH + m * SATP_STR + half * 8;       // jt=0 row base; jt=1: +32*STR
    const f16* A0l = sL + m * SATP_STR + half * 8;
    const f16x8* BH = (const f16x8*)gHi + half * 128 + gh * 64 + m;  // gt=1: +32; per t: +256
    const f16x8* BL = (const f16x8*)gLo + half * 128 + gh * 64 + m;

    f32x16 z;
    #pragma unroll
    for (int r = 0; r < 16; ++r) z[r] = 0.f;
    f32x16 h00 = z, h01 = z, h10 = z, h11 = z, x00 = z, x01 = z, x10 = z, x11 = z;

    const int t0 = wave * 32;
    int ao = (t0 >> 2) * SATP_STR + (t0 & 3) * 16;
    f16x8 ah0 = *(const f16x8*)(A0h + ao);
    f16x8 ah1 = *(const f16x8*)(A0h + 32 * SATP_STR + ao);
    f16x8 al0 = *(const f16x8*)(A0l + ao);
    f16x8 al1 = *(const f16x8*)(A0l + 32 * SATP_STR + ao);
    f16x8 bh0 = BH[256 * t0], bh1 = BH[256 * t0 + 32];
    f16x8 bl0 = BL[256 * t0], bl1 = BL[256 * t0 + 32];

    for (int t = t0; t < t0 + 32; ++t) {
        f16x8 nah0 = ah0, nah1 = ah1, nal0 = al0, nal1 = al1;
        f16x8 nbh0 = bh0, nbh1 = bh1, nbl0 = bl0, nbl1 = bl1;
        if (t + 1 < t0 + 32) {
            int tn = t + 1;
            int an = (tn >> 2) * SATP_STR + (tn & 3) * 16;
            nah0 = *(const f16x8*)(A0h + an);
            nah1 = *(const f16x8*)(A0h + 32 * SATP_STR + an);
            nal0 = *(const f16x8*)(A0l + an);
            nal1 = *(const f16x8*)(A0l + 32 * SATP_STR + an);
            nbh0 = BH[256 * tn]; nbh1 = BH[256 * tn + 32];
            nbl0 = BL[256 * tn]; nbl1 = BL[256 * tn + 32];
        }
        h00 = MFMA(ah0, bh0, h00);
        h01 = MFMA(ah0, bh1, h01);
        h10 = MFMA(ah1, bh0, h10);
        h11 = MFMA(ah1, bh1, h11);
        x00 = MFMA(ah0, bl0, x00); x00 = MFMA(al0, bh0, x00);
        x01 = MFMA(ah0, bl1, x01); x01 = MFMA(al0, bh1, x01);
        x10 = MFMA(ah1, bl0, x10); x10 = MFMA(al1, bh0, x10);
        x11 = MFMA(ah1, bl1, x11); x11 = MFMA(al1, bh1, x11);
        ah0 = nah0; ah1 = nah1; al0 = nal0; al1 = nal1;
        bh0 = nbh0; bh1 = nbh1; bl0 = nbl0; bl1 = nbl1;
    }
    h00 = h00 + x00; h01 = h01 + x01; h10 = h10 + x10; h11 = h11 + x11;

    // ---- flat 8-partial reduce (satP dead; red reuses smem) ----
    __syncthreads();
    float* rw = red + wave * 4096;
    #pragma unroll
    for (int r = 0; r < 16; ++r) {
        int j0 = (r & 3) + 8 * (r >> 2) + 4 * half;      // j within 32-tile
        rw[j0 * 64 + m]           = h00[r];
        rw[j0 * 64 + 32 + m]      = h01[r];
        rw[(j0 + 32) * 64 + m]      = h10[r];
        rw[(j0 + 32) * 64 + 32 + m] = h11[r];
    }
    __syncthreads();
    #pragma unroll
    for (int i = 0; i < 8; ++i) {
        int c = i * 512 + tid;                           // j = c>>6, g = c&63
        float v = red[c]         + red[c + 4096]  + red[c + 8192]  + red[c + 12288]
                + red[c + 16384] + red[c + 20480] + red[c + 24576] + red[c + 28672];
        red[c] = v;                                      // own-cell only: race-free
    }
    __syncthreads();

    // ---- argmax over j (first occurrence), distance + orien ----
    if (tid < 64) {
        int g = tid;
        float best = red[g];
        int bj = 0;
        for (int j = 1; j < 64; ++j) {
            float v = red[j * 64 + g];
            if (v > best) { best = v; bj = j; }
        }
        float dot = best * rnormS;
        int gg = gh * 64 + g;
        out[DIST_OFF + gg * 128 + s] = 2.f - 2.f * dot;
        out[ORI_OFF + s * 128 + gg]  = (float)bj;
    }
}

// Fallback passthrough copies (when grdF was staged inside d_out's sat region)
__global__ void copy_k(const float4* __restrict__ a, const float4* __restrict__ b,
                       float4* __restrict__ out) {
    int i = blockIdx.x * 256 + threadIdx.x;
    out[i] = a[i];
    out[131072 + i] = b[i];
}

extern "C" void kernel_launch(void* const* d_in, const int* in_sizes, int n_in,
                              void* d_out, int out_size, void* d_ws, size_t ws_size,
                              hipStream_t stream) {
    const float* sat = (const float*)d_in[0];
    const float* grd = (const float*)d_in[1];
    float* out = (float*)d_out;

    const bool useWs = (ws_size >= (size_t)2 * 1024 * 1024);
    f16* gHi;
    f16* gLo;
    if (useWs) {
        gHi = (f16*)d_ws;
        gLo = gHi + 524288;
    } else {
        gHi = (f16*)out;                 // floats [0, 262144)
        gLo = (f16*)(out + 262144);      // floats [262144, 524288)
    }

    // prep (+ fused copies when grdF lives in d_ws)
    prep_k<<<useWs ? 576 : 64, 256, 0, stream>>>(grd, gHi, gLo,
                                                 (const float4*)sat, (const float4*)grd,
                                                 (float4*)out);
    corr_k<<<256, 512, 0, stream>>>(sat, gHi, gLo, out);
    if (!useWs)
        copy_k<<<512, 256, 0, stream>>>((const float4*)sat, (const float4*)grd, (float4*)out);
}

// Round 5
// 86.887 us; speedup vs baseline: 2.2690x; 1.0065x over previous
//
#include <hip/hip_runtime.h>
#include <math.h>

typedef _Float16 f16;
typedef __attribute__((ext_vector_type(8))) _Float16 f16x8;
typedef __attribute__((ext_vector_type(16))) float f32x16;

// sat (128,4,64,16) f32, grd (128,4,64,16) f32
// out (f32): sat 524288 | grd 524288 | distance[g][s] 16384 | orien[s][g] 16384
#define DIST_OFF  1048576
#define ORI_OFF   1064960
#define SATP_STR  72      // f16 elems per satP row (144 B, 16B-multiple)

#define MFMA(a,b,c) __builtin_amdgcn_mfma_f32_32x32x16_f16((a),(b),(c),0,0,0)

// ---- prep: grd -> frag-ready grdF[kb][g][e] hi/lo (k = dw*64 + h*16 + c), LDS-tiled ----
// blocks 0..63: transpose/convert.  blocks 64..575 (optional): passthrough copies.
__global__ __launch_bounds__(256) void prep_k(const float* __restrict__ grd,
                                              f16* __restrict__ gHi, f16* __restrict__ gLo,
                                              const float4* __restrict__ satIn,
                                              const float4* __restrict__ grdIn,
                                              float4* __restrict__ out4) {
    const int b = blockIdx.x;
    if (b >= 64) {
        int i = (b - 64) * 256 + threadIdx.x;   // 0..131071 float4
        out4[i] = satIn[i];
        out4[131072 + i] = grdIn[i];
        return;
    }
    __shared__ f16 tH[8192], tL[8192];          // [kb_l 64][g_l 16][e 8]
    const int tid = threadIdx.x;
    const int g0 = (b & 7) * 16;
    const int kq = b >> 3;                      // k-range [kq*512, kq*512+512)
    #pragma unroll
    for (int i = 0; i < 32; ++i) {
        int flat = i * 256 + tid;               // [g_l 16][h 4][j 128], coalesced reads
        int g_l = flat >> 9;
        int r   = flat & 511;
        int h   = r >> 7;
        int j   = r & 127;                      // dw_l = j>>4, c = j&15
        float v = grd[(((g0 + g_l) * 4 + h) * 64 + kq * 8) * 16 + j];
        int k_l = (j >> 4) * 64 + h * 16 + (j & 15);
        f16 hv = (f16)v;
        int a = (k_l >> 3) * 128 + g_l * 8 + (k_l & 7);
        tH[a] = hv;
        tL[a] = (f16)(v - (float)hv);
    }
    __syncthreads();
    #pragma unroll
    for (int i = 0; i < 4; ++i) {
        int f = i * 256 + tid;                  // frag: kb_l = f>>4, g_l = f&15
        int dst = (kq * 64 + (f >> 4)) * 128 + g0 + (f & 15);
        ((f16x8*)gHi)[dst] = *(const f16x8*)(tH + f * 8);
        ((f16x8*)gLo)[dst] = *(const f16x8*)(tL + f * 8);
    }
}

// ---- corr: block=(s, g-half64), 8 waves = 8-way K split, wave tile 64j x 64g ----
__global__ __launch_bounds__(512, 2) void corr_k(const float* __restrict__ sat,
                                                 const f16* __restrict__ gHi,
                                                 const f16* __restrict__ gLo,
                                                 float* __restrict__ out) {
    __shared__ __align__(16) unsigned char smem[131072];  // satP (36.6KB) then red (128KB)
    __shared__ float wred[8];
    __shared__ float rnormS;
    f16* sH = (f16*)smem;                 // [w' 0..126][hc 0..63], stride 72
    f16* sL = sH + 127 * SATP_STR;
    float* red = (float*)smem;            // [kh 8][j 64][g 64]

    const int tid = threadIdx.x;
    const int s  = blockIdx.x >> 1;
    const int gh = blockIdx.x & 1;
    const int wave = tid >> 6, lane = tid & 63;
    const int m = lane & 31, half = lane >> 5;

    // ---- stage satP hi/lo (doubled along w) + ||sat[s]||^2 ----
    const float* satS = sat + s * 4096;
    float ssq = 0.f;
    #pragma unroll
    for (int r = 0; r < 8; ++r) {
        int idx = r * 512 + tid;
        float v = satS[idx];
        int h = idx >> 10, w = (idx >> 4) & 63, c = idx & 15;
        int col = h * 16 + c;
        f16 hv = (f16)v, lv = (f16)(v - (float)hv);
        sH[w * SATP_STR + col] = hv;
        sL[w * SATP_STR + col] = lv;
        if (w < 63) { sH[(w + 64) * SATP_STR + col] = hv; sL[(w + 64) * SATP_STR + col] = lv; }
        ssq += v * v;
    }
    #pragma unroll
    for (int off = 32; off > 0; off >>= 1) ssq += __shfl_down(ssq, off, 64);
    if (lane == 0) wred[wave] = ssq;
    __syncthreads();
    if (tid == 0) {
        float t = 0.f;
        #pragma unroll
        for (int i = 0; i < 8; ++i) t += wred[i];
        rnormS = 1.f / fmaxf(sqrtf(t), 1e-12f);
    }

    // ---- K-loop: kh = wave, 32 k-tiles of 16; branchless copy-free double buffer ----
    const f16* A0h = sH + m * SATP_STR + half * 8;
    const f16* A0l = sL + m * SATP_STR + half * 8;
    const f16x8* BHp = (const f16x8*)gHi;
    const f16x8* BLp = (const f16x8*)gLo;
    const int ggBase = half * 128 + gh * 64 + m;     // + t*256 per tile, +32 for gt=1

    f32x16 z;
    #pragma unroll
    for (int r = 0; r < 16; ++r) z[r] = 0.f;
    f32x16 h00 = z, h01 = z, h10 = z, h11 = z, x00 = z, x01 = z, x10 = z, x11 = z;

    f16x8 ah[2][2], al[2][2], bh[2][2], bl[2][2];

#define LOADT(p, t) { \
    int tc = (t) > 255 ? 255 : (t); \
    int ao = (tc >> 2) * SATP_STR + (tc & 3) * 16; \
    ah[p][0] = *(const f16x8*)(A0h + ao); \
    ah[p][1] = *(const f16x8*)(A0h + ao + 32 * SATP_STR); \
    al[p][0] = *(const f16x8*)(A0l + ao); \
    al[p][1] = *(const f16x8*)(A0l + ao + 32 * SATP_STR); \
    int bu = tc * 256 + ggBase; \
    bh[p][0] = BHp[bu]; bh[p][1] = BHp[bu + 32]; \
    bl[p][0] = BLp[bu]; bl[p][1] = BLp[bu + 32]; }

#define STEP(p) { \
    h00 = MFMA(ah[p][0], bh[p][0], h00); \
    h01 = MFMA(ah[p][0], bh[p][1], h01); \
    h10 = MFMA(ah[p][1], bh[p][0], h10); \
    h11 = MFMA(ah[p][1], bh[p][1], h11); \
    x00 = MFMA(ah[p][0], bl[p][0], x00); x00 = MFMA(al[p][0], bh[p][0], x00); \
    x01 = MFMA(ah[p][0], bl[p][1], x01); x01 = MFMA(al[p][0], bh[p][1], x01); \
    x10 = MFMA(ah[p][1], bl[p][0], x10); x10 = MFMA(al[p][1], bh[p][0], x10); \
    x11 = MFMA(ah[p][1], bl[p][1], x11); x11 = MFMA(al[p][1], bh[p][1], x11); }

    const int t0 = wave * 32;
    LOADT(0, t0)
    #pragma unroll 4
    for (int t = t0; t < t0 + 32; t += 2) {
        LOADT(1, t + 1)
        STEP(0)
        LOADT(0, t + 2)     // clamped; last iteration's extra load is unused
        STEP(1)
    }
    h00 = h00 + x00; h01 = h01 + x01; h10 = h10 + x10; h11 = h11 + x11;

    // ---- flat 8-partial reduce (satP dead; red reuses smem) ----
    __syncthreads();
    float* rw = red + wave * 4096;
    #pragma unroll
    for (int r = 0; r < 16; ++r) {
        int j0 = (r & 3) + 8 * (r >> 2) + 4 * half;      // j within 32-tile
        rw[j0 * 64 + m]             = h00[r];
        rw[j0 * 64 + 32 + m]        = h01[r];
        rw[(j0 + 32) * 64 + m]      = h10[r];
        rw[(j0 + 32) * 64 + 32 + m] = h11[r];
    }
    __syncthreads();
    #pragma unroll
    for (int i = 0; i < 8; ++i) {
        int c = i * 512 + tid;                           // j = c>>6, g = c&63
        float v = red[c]         + red[c + 4096]  + red[c + 8192]  + red[c + 12288]
                + red[c + 16384] + red[c + 20480] + red[c + 24576] + red[c + 28672];
        red[c] = v;                                      // own-cell only: race-free
    }
    __syncthreads();

    // ---- argmax over j (first occurrence), distance + orien ----
    if (tid < 64) {
        int g = tid;
        float best = red[g];
        int bj = 0;
        for (int j = 1; j < 64; ++j) {
            float v = red[j * 64 + g];
            if (v > best) { best = v; bj = j; }
        }
        float dot = best * rnormS;
        int gg = gh * 64 + g;
        out[DIST_OFF + gg * 128 + s] = 2.f - 2.f * dot;
        out[ORI_OFF + s * 128 + gg]  = (float)bj;
    }
}

// Fallback passthrough copies (when grdF was staged inside d_out's sat region)
__global__ void copy_k(const float4* __restrict__ a, const float4* __restrict__ b,
                       float4* __restrict__ out) {
    int i = blockIdx.x * 256 + threadIdx.x;
    out[i] = a[i];
    out[131072 + i] = b[i];
}

extern "C" void kernel_launch(void* const* d_in, const int* in_sizes, int n_in,
                              void* d_out, int out_size, void* d_ws, size_t ws_size,
                              hipStream_t stream) {
    const float* sat = (const float*)d_in[0];
    const float* grd = (const float*)d_in[1];
    float* out = (float*)d_out;

    const bool useWs = (ws_size >= (size_t)2 * 1024 * 1024);
    f16* gHi;
    f16* gLo;
    if (useWs) {
        gHi = (f16*)d_ws;
        gLo = gHi + 524288;
    } else {
        gHi = (f16*)out;                 // floats [0, 262144)
        gLo = (f16*)(out + 262144);      // floats [262144, 524288)
    }

    // prep (+ fused copies when grdF lives in d_ws)
    prep_k<<<useWs ? 576 : 64, 256, 0, stream>>>(grd, gHi, gLo,
                                                 (const float4*)sat, (const float4*)grd,
                                                 (float4*)out);
    corr_k<<<256, 512, 0, stream>>>(sat, gHi, gLo, out);
    if (!useWs)
        copy_k<<<512, 256, 0, stream>>>((const float4*)sat, (const float4*)grd, (float4*)out);
}